// Round 16
// baseline (568.489 us; speedup 1.0000x reference)
//
#include <hip/hip_runtime.h>

#define DD 64
#define EPB 1024  // edges per block in fill pipeline

__device__ __forceinline__ unsigned enc_f32(float x) {
  unsigned u = __float_as_uint(x);
  return (u & 0x80000000u) ? ~u : (u | 0x80000000u);
}
__device__ __forceinline__ float dec_f32(unsigned k) {
  return (k & 0x80000000u) ? __uint_as_float(k ^ 0x80000000u)
                           : __uint_as_float(~k);
}
__device__ __forceinline__ unsigned f2bf(float x) {
  unsigned u = __float_as_uint(x);
  return (u + 0x7fffu + ((u >> 16) & 1u)) >> 16;
}
__device__ __forceinline__ void unpack8(const uint4 raw, float* v) {
  v[0] = __uint_as_float(raw.x << 16);
  v[1] = __uint_as_float(raw.x & 0xffff0000u);
  v[2] = __uint_as_float(raw.y << 16);
  v[3] = __uint_as_float(raw.y & 0xffff0000u);
  v[4] = __uint_as_float(raw.z << 16);
  v[5] = __uint_as_float(raw.z & 0xffff0000u);
  v[6] = __uint_as_float(raw.w << 16);
  v[7] = __uint_as_float(raw.w & 0xffff0000u);
}
__device__ __forceinline__ float4 unpack4(const uint2 r) {
  return make_float4(__uint_as_float(r.x << 16),
                     __uint_as_float(r.x & 0xffff0000u),
                     __uint_as_float(r.y << 16),
                     __uint_as_float(r.y & 0xffff0000u));
}

// ================= f32 -> bf16 conversion (h0) =================
__global__ __launch_bounds__(256) void conv_bf16(const float* __restrict__ x,
                                                 ushort* __restrict__ xb,
                                                 int n4) {
  int i = blockIdx.x * 256 + threadIdx.x;
  if (i < n4) {
    float4 v = ((const float4*)x)[i];
    uint2 o;
    o.x = f2bf(v.x) | (f2bf(v.y) << 16);
    o.y = f2bf(v.z) | (f2bf(v.w) << 16);
    ((uint2*)xb)[i] = o;
  }
}

// ---- coarse scatter: LDS-reordered, fixed-capacity bucket runs (4B records) ----
__global__ __launch_bounds__(256) void f2_coarse(
    const int* __restrict__ src, const int* __restrict__ dst,
    const int* __restrict__ et, int* __restrict__ gcur,
    unsigned* __restrict__ staging, int E) {
  __shared__ int lcnt[256];
  __shared__ int sc[256];
  __shared__ int lbase[256];
  __shared__ int gb[256];
  __shared__ unsigned rec[EPB];
  __shared__ unsigned char rbk[EPB];

  const int t = threadIdx.x;
  const int base = blockIdx.x * EPB;
  const int bc = min(EPB, E - base);

  lcnt[t] = 0;
  __syncthreads();

  int d_[EPB / 256], se_[EPB / 256], rk_[EPB / 256];
#pragma unroll
  for (int k = 0; k < EPB / 256; ++k) {
    const int e = base + k * 256 + t;
    if (e < E) {
      const int d = dst[e];
      d_[k] = d;
      se_[k] = (src[e] << 2) | et[e];
      rk_[k] = atomicAdd(&lcnt[d >> 8], 1);
    } else {
      d_[k] = -1;
    }
  }
  __syncthreads();

  const int lv = lcnt[t];
  sc[t] = lv;
  __syncthreads();
#pragma unroll
  for (int off = 1; off < 256; off <<= 1) {
    const int add = (t >= off) ? sc[t - off] : 0;
    __syncthreads();
    sc[t] += add;
    __syncthreads();
  }
  lbase[t] = sc[t] - lv;
  gb[t] = lv ? atomicAdd(&gcur[t], lv) : 0;
  __syncthreads();

#pragma unroll
  for (int k = 0; k < EPB / 256; ++k) {
    if (d_[k] >= 0) {
      const int cb = d_[k] >> 8;
      const int pos = lbase[cb] + rk_[k];
      rec[pos] = ((unsigned)(d_[k] & 255) << 24) | (unsigned)se_[k];
      rbk[pos] = (unsigned char)cb;
    }
  }
  __syncthreads();

  for (int idx = t; idx < bc; idx += 256) {
    const int cb = rbk[idx];
    staging[gb[cb] + (idx - lbase[cb])] = rec[idx];
  }
}

// ---- scan bucket counts (from gcur) -> cbase; set rowptr[N] ----
__global__ __launch_bounds__(256) void cscan2(const int* __restrict__ gcur,
                                              int* __restrict__ cbase,
                                              int* __restrict__ rowptr, int N,
                                              int E, int CAP) {
  __shared__ int s[256];
  const int t = threadIdx.x;
  const int c = gcur[t] - t * CAP;
  s[t] = c;
  __syncthreads();
#pragma unroll
  for (int off = 1; off < 256; off <<= 1) {
    const int add = (t >= off) ? s[t - off] : 0;
    __syncthreads();
    s[t] += add;
    __syncthreads();
  }
  cbase[t] = s[t] - c;
  if (t == 0) rowptr[N] = E;
}

// ---- fine placement, 4 sub-blocks per bucket, (dst,rel)-sorted output ----
__global__ __launch_bounds__(256) void f3_fine4(
    const unsigned* __restrict__ staging, const int* __restrict__ gcur,
    const int* __restrict__ cbase, int* __restrict__ rowptr,
    int* __restrict__ srcet, int N, int CAP) {
  __shared__ int hist[256];
  __shared__ int sc[256];
  __shared__ int lcur[256];
  __shared__ int before;
  const int cb = blockIdx.x >> 2;
  const int sub = blockIdx.x & 3;
  const int t = threadIdx.x;
  const int s0 = cb * CAP;
  const int s1 = gcur[cb];
  const int dlo = sub << 6;

  hist[t] = 0;
  if (t == 0) before = 0;
  __syncthreads();

  int myb = 0;
  for (int i = s0 + t; i < s1; i += 256) {
    const unsigned r = staging[i];
    const int dl = (int)(r >> 24);
    const int off = dl - dlo;
    if ((unsigned)off < 64u)
      atomicAdd(&hist[(off << 2) | (int)(r & 3u)], 1);
    else if (dl < dlo)
      ++myb;
  }
#pragma unroll
  for (int off = 32; off > 0; off >>= 1) myb += __shfl_down(myb, off);
  if ((t & 63) == 0 && myb) atomicAdd(&before, myb);
  __syncthreads();

  const int v = hist[t];
  sc[t] = v;
  __syncthreads();
#pragma unroll
  for (int off = 1; off < 256; off <<= 1) {
    const int add = (t >= off) ? sc[t - off] : 0;
    __syncthreads();
    sc[t] += add;
    __syncthreads();
  }
  const int base = cbase[cb] + before + sc[t] - v;
  lcur[t] = base;
  if ((t & 3) == 0) {
    const int dn = (cb << 8) + dlo + (t >> 2);
    if (dn < N) rowptr[dn] = base;
  }
  __syncthreads();

  for (int i = s0 + t; i < s1; i += 256) {
    const unsigned r = staging[i];
    const int dl = (int)(r >> 24);
    const int off = dl - dlo;
    if ((unsigned)off < 64u) {
      const int pos = atomicAdd(&lcur[(off << 2) | (int)(r & 3u)], 1);
      srcet[pos] = (int)(r & 0xFFFFFFu);
    }
  }
}

// ====== per-node relation gather (bf16 rows, 16 lanes/edge, 4 in flight) ======
#define ACCUM(se, v)                                                         \
  {                                                                          \
    const int r_ = (se) & 3;                                                 \
    if (r_ == 0) { a0.x += v.x; a0.y += v.y; a0.z += v.z; a0.w += v.w; }     \
    else if (r_ == 1) { a1.x += v.x; a1.y += v.y; a1.z += v.z; a1.w += v.w; }\
    else if (r_ == 2) { a2.x += v.x; a2.y += v.y; a2.z += v.z; a2.w += v.w; }\
    else { a3.x += v.x; a3.y += v.y; a3.z += v.z; a3.w += v.w; }             \
  }

__global__ __launch_bounds__(256) void gather_rel(
    const ushort* __restrict__ hb, const int* __restrict__ rowptr,
    const int* __restrict__ srcet, ushort* __restrict__ aggr_bf, int N) {
  const int n = blockIdx.x * 4 + (threadIdx.x >> 6);
  const int lane = threadIdx.x & 63;
  const int g = lane >> 4;    // edge slot 0..3
  const int t = lane & 15;    // elements [4t, 4t+4)
  if (n >= N) return;
  const int beg = rowptr[n], end = rowptr[n + 1];

  float4 a0 = make_float4(0.f, 0.f, 0.f, 0.f);
  float4 a1 = a0, a2 = a0, a3 = a0;

  int j = beg + g;
  for (; j + 12 < end; j += 16) {
    const int se0 = srcet[j];
    const int se1 = srcet[j + 4];
    const int se2 = srcet[j + 8];
    const int se3 = srcet[j + 12];
    const uint2 r0 = *(const uint2*)(hb + ((size_t)(se0 >> 2) << 6) + (t << 2));
    const uint2 r1 = *(const uint2*)(hb + ((size_t)(se1 >> 2) << 6) + (t << 2));
    const uint2 r2 = *(const uint2*)(hb + ((size_t)(se2 >> 2) << 6) + (t << 2));
    const uint2 r3 = *(const uint2*)(hb + ((size_t)(se3 >> 2) << 6) + (t << 2));
    const float4 v0 = unpack4(r0);
    const float4 v1 = unpack4(r1);
    const float4 v2 = unpack4(r2);
    const float4 v3 = unpack4(r3);
    ACCUM(se0, v0);
    ACCUM(se1, v1);
    ACCUM(se2, v2);
    ACCUM(se3, v3);
  }
  for (; j < end; j += 4) {
    const int se0 = srcet[j];
    const uint2 r0 = *(const uint2*)(hb + ((size_t)(se0 >> 2) << 6) + (t << 2));
    const float4 v0 = unpack4(r0);
    ACCUM(se0, v0);
  }

#pragma unroll
  for (int off = 16; off <= 32; off <<= 1) {
    a0.x += __shfl_xor(a0.x, off); a0.y += __shfl_xor(a0.y, off);
    a0.z += __shfl_xor(a0.z, off); a0.w += __shfl_xor(a0.w, off);
    a1.x += __shfl_xor(a1.x, off); a1.y += __shfl_xor(a1.y, off);
    a1.z += __shfl_xor(a1.z, off); a1.w += __shfl_xor(a1.w, off);
    a2.x += __shfl_xor(a2.x, off); a2.y += __shfl_xor(a2.y, off);
    a2.z += __shfl_xor(a2.z, off); a2.w += __shfl_xor(a2.w, off);
    a3.x += __shfl_xor(a3.x, off); a3.y += __shfl_xor(a3.y, off);
    a3.z += __shfl_xor(a3.z, off); a3.w += __shfl_xor(a3.w, off);
  }

  const float4 res = (g == 0) ? a0 : (g == 1) ? a1 : (g == 2) ? a2 : a3;
  uint2 p;
  p.x = f2bf(res.x) | (f2bf(res.y) << 16);
  p.y = f2bf(res.z) | (f2bf(res.w) << 16);
  *(uint2*)(aggr_bf + ((size_t)n << 8) + (g << 6) + (t << 2)) = p;
}

// == dense (LDS-tiled, bf16 in/out): hb_out = bf16(relu(sum_r aggr@Wrel + h@Wloop + b)) ==
__global__ __launch_bounds__(256) void rgcn_dense_t(
    const ushort* __restrict__ aggr_bf, const ushort* __restrict__ hb_in,
    const float* __restrict__ Wrel, const float* __restrict__ Wloop,
    const float* __restrict__ brel, ushort* __restrict__ hb_out, int N) {
  __shared__ float tile[64 * 65];
  const int tid = threadIdx.x;
  const int lane = tid & 63;
  const int wv = tid >> 6;
  const int c0 = __builtin_amdgcn_readfirstlane(wv << 4);
  const int n0 = blockIdx.x * 64;

  float acc[16];
#pragma unroll
  for (int jj = 0; jj < 16; ++jj) acc[jj] = brel[c0 + jj];

#pragma unroll 1
  for (int m = 0; m < 5; ++m) {
    __syncthreads();
#pragma unroll
    for (int q = 0; q < 2; ++q) {
      const int f = q * 256 + tid;  // 0..511
      const int row = f >> 3;       // 0..63
      const int c8 = (f & 7) << 3;  // 0..56
      const int nn = n0 + row;
      float v[8] = {0.f, 0.f, 0.f, 0.f, 0.f, 0.f, 0.f, 0.f};
      if (nn < N) {
        const ushort* s = (m < 4) ? (aggr_bf + ((size_t)nn << 8) + (m << 6) + c8)
                                  : (hb_in + ((size_t)nn << 6) + c8);
        const uint4 raw = *(const uint4*)s;
        unpack8(raw, v);
      }
      float* d = tile + row * 65 + c8;
#pragma unroll
      for (int k = 0; k < 8; ++k) d[k] = v[k];
    }
    __syncthreads();
    const float* __restrict__ W =
        (m < 4) ? (Wrel + (size_t)m * DD * DD) : Wloop;
    const float* trow = tile + lane * 65;
#pragma unroll
    for (int k = 0; k < DD; ++k) {
      const float hk = trow[k];
#pragma unroll
      for (int jj = 0; jj < 16; ++jj)
        acc[jj] = fmaf(hk, W[k * DD + c0 + jj], acc[jj]);
    }
  }

  __syncthreads();
  {
    float* d = tile + lane * 65 + c0;
#pragma unroll
    for (int jj = 0; jj < 16; ++jj) d[jj] = fmaxf(acc[jj], 0.f);
  }
  __syncthreads();
#pragma unroll
  for (int q = 0; q < 2; ++q) {
    const int f = q * 256 + tid;
    const int row = f >> 3;
    const int c8 = (f & 7) << 3;
    const int nn = n0 + row;
    if (nn < N) {
      const float* s = tile + row * 65 + c8;
      uint4 p;
      p.x = f2bf(s[0]) | (f2bf(s[1]) << 16);
      p.y = f2bf(s[2]) | (f2bf(s[3]) << 16);
      p.z = f2bf(s[4]) | (f2bf(s[5]) << 16);
      p.w = f2bf(s[6]) | (f2bf(s[7]) << 16);
      *(uint4*)(hb_out + ((size_t)nn << 6) + c8) = p;
    }
  }
}

// ===== GAT projection (LDS-tiled, bf16 in): el/er/y per node + global max(el) =====
// y[n] = (h[n]@Wg) . Wd  — z is never materialized (head is linear in hg).
__global__ __launch_bounds__(256) void gemm_gat_t(
    const ushort* __restrict__ hb_in, const float* __restrict__ Wg,
    const float* __restrict__ al, const float* __restrict__ ar,
    const float* __restrict__ Wd, float* __restrict__ el,
    float* __restrict__ er, float* __restrict__ y,
    unsigned* __restrict__ genc, int N) {
  __shared__ float tile[64 * 65];
  __shared__ float sel[4][64];
  __shared__ float ser[4][64];
  __shared__ float sy[4][64];
  const int tid = threadIdx.x;
  const int lane = tid & 63;
  const int wv = tid >> 6;
  const int c0 = __builtin_amdgcn_readfirstlane(wv << 4);
  const int n0 = blockIdx.x * 64;
  const int n = n0 + lane;

#pragma unroll
  for (int q = 0; q < 2; ++q) {
    const int f = q * 256 + tid;
    const int row = f >> 3;
    const int c8 = (f & 7) << 3;
    const int nn = n0 + row;
    float v[8] = {0.f, 0.f, 0.f, 0.f, 0.f, 0.f, 0.f, 0.f};
    if (nn < N) {
      const uint4 raw = *(const uint4*)(hb_in + ((size_t)nn << 6) + c8);
      unpack8(raw, v);
    }
    float* d = tile + row * 65 + c8;
#pragma unroll
    for (int k = 0; k < 8; ++k) d[k] = v[k];
  }
  __syncthreads();

  float acc[16];
#pragma unroll
  for (int jj = 0; jj < 16; ++jj) acc[jj] = 0.f;
  {
    const float* trow = tile + lane * 65;
#pragma unroll
    for (int k = 0; k < DD; ++k) {
      const float hk = trow[k];
#pragma unroll
      for (int jj = 0; jj < 16; ++jj)
        acc[jj] = fmaf(hk, Wg[k * DD + c0 + jj], acc[jj]);
    }
  }

  float pl = 0.f, pr = 0.f, py = 0.f;
#pragma unroll
  for (int jj = 0; jj < 16; ++jj) {
    pl = fmaf(acc[jj], al[c0 + jj], pl);
    pr = fmaf(acc[jj], ar[c0 + jj], pr);
    py = fmaf(acc[jj], Wd[c0 + jj], py);
  }
  sel[wv][lane] = pl;
  ser[wv][lane] = pr;
  sy[wv][lane] = py;
  __syncthreads();
  if (wv == 0) {
    float eln = sel[0][lane] + sel[1][lane] + sel[2][lane] + sel[3][lane];
    float ern = ser[0][lane] + ser[1][lane] + ser[2][lane] + ser[3][lane];
    float yn = sy[0][lane] + sy[1][lane] + sy[2][lane] + sy[3][lane];
    if (n < N) {
      el[n] = eln;
      er[n] = ern;
      y[n] = yn;
    }
    float mx = (n < N) ? eln : -1e30f;
#pragma unroll
    for (int off = 32; off > 0; off >>= 1) mx = fmaxf(mx, __shfl_xor(mx, off));
    if (lane == 0) atomicMax(genc, enc_f32(mx));
  }
}

// ===== scalar GAT aggregation + pooling: out[g] += sum_n (sum_s w*y[s]) / (sum_s w) =====
// wave per node, edge per lane; el/y tables are 200 KB (L2-resident).
#define GSC_NPB 128
__global__ __launch_bounds__(256) void gat_scalar(
    const float* __restrict__ el, const float* __restrict__ er,
    const float* __restrict__ y, const int* __restrict__ rowptr,
    const int* __restrict__ srcet, const unsigned* __restrict__ genc,
    const int* __restrict__ gids, float* __restrict__ out, int N, int B) {
  __shared__ float acc[256];
  for (int i = threadIdx.x; i < B; i += 256) acc[i] = 0.f;
  __syncthreads();
  const int wv = threadIdx.x >> 6;
  const int lane = threadIdx.x & 63;
  const float gmax = dec_f32(*genc);
  const int base = blockIdx.x * GSC_NPB;

  for (int i = wv; i < GSC_NPB; i += 4) {
    const int n = base + i;
    if (n >= N) break;
    const int beg = rowptr[n], end = rowptr[n + 1];
    const float ern = er[n];
    float mb = gmax + ern;  // upper bound on leaky(el[s]+ern): leaky monotone
    mb = (mb > 0.f) ? mb : 0.2f * mb;
    float num = 0.f, den = 0.f;
    for (int j = beg + lane; j < end; j += 64) {
      const int s = srcet[j] >> 2;
      float x = el[s] + ern;
      x = (x > 0.f) ? x : 0.2f * x;
      const float w = __expf(x - mb);
      num = fmaf(w, y[s], num);
      den += w;
    }
#pragma unroll
    for (int off = 32; off > 0; off >>= 1) {
      num += __shfl_xor(num, off);
      den += __shfl_xor(den, off);
    }
    if (lane == 0) atomicAdd(&acc[gids[n]], num / fmaxf(den, 1e-9f));
  }
  __syncthreads();
  for (int i = threadIdx.x; i < B; i += 256) {
    const float v = acc[i];
    if (v != 0.f) unsafeAtomicAdd(out + i, v);
  }
}

__global__ void init_out_k(float* out, const float* bd, int n, unsigned* genc,
                           int* gcur, int CAP) {
  int i = blockIdx.x * blockDim.x + threadIdx.x;
  if (i < n) out[i] = bd[0];
  if (i < 256) gcur[i] = i * CAP;
  if (i == 0) *genc = enc_f32(-1e30f);
}

// ================= launch =================
extern "C" void kernel_launch(void* const* d_in, const int* in_sizes, int n_in,
                              void* d_out, int out_size, void* d_ws,
                              size_t ws_size, hipStream_t stream) {
  const float* h0 = (const float*)d_in[0];
  const float* Wrel = (const float*)d_in[1];
  const float* Wloop = (const float*)d_in[2];
  const float* brel = (const float*)d_in[3];
  const float* Wg = (const float*)d_in[4];
  const float* al = (const float*)d_in[5];
  const float* ar = (const float*)d_in[6];
  const float* Wd = (const float*)d_in[7];
  const float* bd = (const float*)d_in[8];
  const int* src = (const int*)d_in[9];
  const int* dst = (const int*)d_in[10];
  const int* et = (const int*)d_in[11];
  const int* gids = (const int*)d_in[12];

  const int N = in_sizes[0] / DD;
  const int E = in_sizes[9];
  const int L = in_sizes[2] / (DD * DD);
  float* out = (float*)d_out;
  const int CAP = (E / 256) * 2;  // fixed bucket capacity (2x mean)

  // ---- workspace layout ----
  char* wsb = (char*)d_ws;
  ushort* hbA = (ushort*)wsb;                    // N*64 bf16
  ushort* hbB = hbA + (size_t)N * DD;            // N*64 bf16
  ushort* aggr_bf = hbB + (size_t)N * DD;        // N*256 bf16 (25.6MB region)
  int* rowptr = (int*)(aggr_bf + (size_t)N * 256);  // N+1
  int* srcet = rowptr + N + 1;                   // E
  float* el = (float*)(srcet + E);               // N
  float* er = el + N;                            // N
  float* yv = er + N;                            // N
  int* gcur = (int*)(yv + N);                    // 256
  int* cbase = gcur + 256;                       // 256
  unsigned* genc = (unsigned*)(cbase + 256);     // 1
  unsigned* staging = (unsigned*)aggr_bf;        // 256*CAP uints (12.8MB)

  dim3 b256(256);
  const int grid_dense = (N + 63) / 64;
  const int grid_n4 = (N + 3) / 4;
  const int nfb = (E + EPB - 1) / EPB;
  const int ncb = (N + 255) >> 8;

  hipLaunchKernelGGL(init_out_k, dim3((max(out_size, 256) + 255) / 256), b256,
                     0, stream, out, bd, out_size, genc, gcur, CAP);

  // ---- CSR build (fixed-capacity buckets, (dst,rel)-sorted output) ----
  hipLaunchKernelGGL(f2_coarse, dim3(nfb), b256, 0, stream, src, dst, et, gcur,
                     staging, E);
  hipLaunchKernelGGL(cscan2, dim3(1), b256, 0, stream, gcur, cbase, rowptr, N,
                     E, CAP);
  hipLaunchKernelGGL(f3_fine4, dim3(ncb * 4), b256, 0, stream, staging, gcur,
                     cbase, rowptr, srcet, N, CAP);

  // ---- h0 -> bf16 ----
  hipLaunchKernelGGL(conv_bf16, dim3((N * DD / 4 + 255) / 256), b256, 0, stream,
                     h0, hbA, N * DD / 4);

  // ---- RGCN layers (bf16 features, f32 accumulate; dense stores post-relu) ----
  ushort* cur = hbA;
  ushort* nxt = hbB;
  for (int l = 0; l < L; ++l) {
    hipLaunchKernelGGL(gather_rel, dim3(grid_n4), b256, 0, stream, cur, rowptr,
                       srcet, aggr_bf, N);
    hipLaunchKernelGGL(rgcn_dense_t, dim3(grid_dense), b256, 0, stream, aggr_bf,
                       cur, Wrel + (size_t)l * 4 * DD * DD,
                       Wloop + (size_t)l * DD * DD, brel + (size_t)l * DD, nxt,
                       N);
    ushort* tmp = cur; cur = nxt; nxt = tmp;
  }

  // ---- GAT: project to el/er/y scalars, then scalar aggregation + pooling ----
  hipLaunchKernelGGL(gemm_gat_t, dim3(grid_dense), b256, 0, stream, cur, Wg, al,
                     ar, Wd, el, er, yv, genc, N);
  const int grid_gs = (N + GSC_NPB - 1) / GSC_NPB;
  hipLaunchKernelGGL(gat_scalar, dim3(grid_gs), b256, 0, stream, el, er, yv,
                     rowptr, srcet, genc, gids, out, N, out_size);
}

// Round 17
// 492.484 us; speedup vs baseline: 1.1543x; 1.1543x over previous
//
#include <hip/hip_runtime.h>

#define DD 64
#define EPB 1024  // edges per block in fill pipeline

__device__ __forceinline__ unsigned enc_f32(float x) {
  unsigned u = __float_as_uint(x);
  return (u & 0x80000000u) ? ~u : (u | 0x80000000u);
}
__device__ __forceinline__ float dec_f32(unsigned k) {
  return (k & 0x80000000u) ? __uint_as_float(k ^ 0x80000000u)
                           : __uint_as_float(~k);
}
__device__ __forceinline__ unsigned f2bf(float x) {
  unsigned u = __float_as_uint(x);
  return (u + 0x7fffu + ((u >> 16) & 1u)) >> 16;
}
__device__ __forceinline__ void unpack8(const uint4 raw, float* v) {
  v[0] = __uint_as_float(raw.x << 16);
  v[1] = __uint_as_float(raw.x & 0xffff0000u);
  v[2] = __uint_as_float(raw.y << 16);
  v[3] = __uint_as_float(raw.y & 0xffff0000u);
  v[4] = __uint_as_float(raw.z << 16);
  v[5] = __uint_as_float(raw.z & 0xffff0000u);
  v[6] = __uint_as_float(raw.w << 16);
  v[7] = __uint_as_float(raw.w & 0xffff0000u);
}
__device__ __forceinline__ float4 unpack4(const uint2 r) {
  return make_float4(__uint_as_float(r.x << 16),
                     __uint_as_float(r.x & 0xffff0000u),
                     __uint_as_float(r.y << 16),
                     __uint_as_float(r.y & 0xffff0000u));
}

// ================= f32 -> bf16 conversion (h0) =================
__global__ __launch_bounds__(256) void conv_bf16(const float* __restrict__ x,
                                                 ushort* __restrict__ xb,
                                                 int n4) {
  int i = blockIdx.x * 256 + threadIdx.x;
  if (i < n4) {
    float4 v = ((const float4*)x)[i];
    uint2 o;
    o.x = f2bf(v.x) | (f2bf(v.y) << 16);
    o.y = f2bf(v.z) | (f2bf(v.w) << 16);
    ((uint2*)xb)[i] = o;
  }
}

// ---- coarse scatter: LDS-reordered, fixed-capacity bucket runs (4B records) ----
__global__ __launch_bounds__(256) void f2_coarse(
    const int* __restrict__ src, const int* __restrict__ dst,
    const int* __restrict__ et, int* __restrict__ gcur,
    unsigned* __restrict__ staging, int E) {
  __shared__ int lcnt[256];
  __shared__ int sc[256];
  __shared__ int lbase[256];
  __shared__ int gb[256];
  __shared__ unsigned rec[EPB];
  __shared__ unsigned char rbk[EPB];

  const int t = threadIdx.x;
  const int base = blockIdx.x * EPB;
  const int bc = min(EPB, E - base);

  lcnt[t] = 0;
  __syncthreads();

  int d_[EPB / 256], se_[EPB / 256], rk_[EPB / 256];
#pragma unroll
  for (int k = 0; k < EPB / 256; ++k) {
    const int e = base + k * 256 + t;
    if (e < E) {
      const int d = dst[e];
      d_[k] = d;
      se_[k] = (src[e] << 2) | et[e];
      rk_[k] = atomicAdd(&lcnt[d >> 8], 1);
    } else {
      d_[k] = -1;
    }
  }
  __syncthreads();

  const int lv = lcnt[t];
  sc[t] = lv;
  __syncthreads();
#pragma unroll
  for (int off = 1; off < 256; off <<= 1) {
    const int add = (t >= off) ? sc[t - off] : 0;
    __syncthreads();
    sc[t] += add;
    __syncthreads();
  }
  lbase[t] = sc[t] - lv;
  gb[t] = lv ? atomicAdd(&gcur[t], lv) : 0;
  __syncthreads();

#pragma unroll
  for (int k = 0; k < EPB / 256; ++k) {
    if (d_[k] >= 0) {
      const int cb = d_[k] >> 8;
      const int pos = lbase[cb] + rk_[k];
      rec[pos] = ((unsigned)(d_[k] & 255) << 24) | (unsigned)se_[k];
      rbk[pos] = (unsigned char)cb;
    }
  }
  __syncthreads();

  for (int idx = t; idx < bc; idx += 256) {
    const int cb = rbk[idx];
    staging[gb[cb] + (idx - lbase[cb])] = rec[idx];
  }
}

// ---- scan bucket counts (from gcur) -> cbase; set rowptr[N] ----
__global__ __launch_bounds__(256) void cscan2(const int* __restrict__ gcur,
                                              int* __restrict__ cbase,
                                              int* __restrict__ rowptr, int N,
                                              int E, int CAP) {
  __shared__ int s[256];
  const int t = threadIdx.x;
  const int c = gcur[t] - t * CAP;
  s[t] = c;
  __syncthreads();
#pragma unroll
  for (int off = 1; off < 256; off <<= 1) {
    const int add = (t >= off) ? s[t - off] : 0;
    __syncthreads();
    s[t] += add;
    __syncthreads();
  }
  cbase[t] = s[t] - c;
  if (t == 0) rowptr[N] = E;
}

// ---- fine placement, 4 sub-blocks per bucket, (dst,rel)-sorted output ----
__global__ __launch_bounds__(256) void f3_fine4(
    const unsigned* __restrict__ staging, const int* __restrict__ gcur,
    const int* __restrict__ cbase, int* __restrict__ rowptr,
    int* __restrict__ srcet, int N, int CAP) {
  __shared__ int hist[256];
  __shared__ int sc[256];
  __shared__ int lcur[256];
  __shared__ int before;
  const int cb = blockIdx.x >> 2;
  const int sub = blockIdx.x & 3;
  const int t = threadIdx.x;
  const int s0 = cb * CAP;
  const int s1 = gcur[cb];
  const int dlo = sub << 6;

  hist[t] = 0;
  if (t == 0) before = 0;
  __syncthreads();

  int myb = 0;
  for (int i = s0 + t; i < s1; i += 256) {
    const unsigned r = staging[i];
    const int dl = (int)(r >> 24);
    const int off = dl - dlo;
    if ((unsigned)off < 64u)
      atomicAdd(&hist[(off << 2) | (int)(r & 3u)], 1);
    else if (dl < dlo)
      ++myb;
  }
#pragma unroll
  for (int off = 32; off > 0; off >>= 1) myb += __shfl_down(myb, off);
  if ((t & 63) == 0 && myb) atomicAdd(&before, myb);
  __syncthreads();

  const int v = hist[t];
  sc[t] = v;
  __syncthreads();
#pragma unroll
  for (int off = 1; off < 256; off <<= 1) {
    const int add = (t >= off) ? sc[t - off] : 0;
    __syncthreads();
    sc[t] += add;
    __syncthreads();
  }
  const int base = cbase[cb] + before + sc[t] - v;
  lcur[t] = base;
  if ((t & 3) == 0) {
    const int dn = (cb << 8) + dlo + (t >> 2);
    if (dn < N) rowptr[dn] = base;
  }
  __syncthreads();

  for (int i = s0 + t; i < s1; i += 256) {
    const unsigned r = staging[i];
    const int dl = (int)(r >> 24);
    const int off = dl - dlo;
    if ((unsigned)off < 64u) {
      const int pos = atomicAdd(&lcur[(off << 2) | (int)(r & 3u)], 1);
      srcet[pos] = (int)(r & 0xFFFFFFu);
    }
  }
}

// ====== per-node relation gather (bf16 rows, 16 lanes/edge, 4 in flight) ======
#define ACCUM(se, v)                                                         \
  {                                                                          \
    const int r_ = (se) & 3;                                                 \
    if (r_ == 0) { a0.x += v.x; a0.y += v.y; a0.z += v.z; a0.w += v.w; }     \
    else if (r_ == 1) { a1.x += v.x; a1.y += v.y; a1.z += v.z; a1.w += v.w; }\
    else if (r_ == 2) { a2.x += v.x; a2.y += v.y; a2.z += v.z; a2.w += v.w; }\
    else { a3.x += v.x; a3.y += v.y; a3.z += v.z; a3.w += v.w; }             \
  }

__global__ __launch_bounds__(256) void gather_rel(
    const ushort* __restrict__ hb, const int* __restrict__ rowptr,
    const int* __restrict__ srcet, ushort* __restrict__ aggr_bf, int N) {
  const int n = blockIdx.x * 4 + (threadIdx.x >> 6);
  const int lane = threadIdx.x & 63;
  const int g = lane >> 4;    // edge slot 0..3
  const int t = lane & 15;    // elements [4t, 4t+4)
  if (n >= N) return;
  const int beg = rowptr[n], end = rowptr[n + 1];

  float4 a0 = make_float4(0.f, 0.f, 0.f, 0.f);
  float4 a1 = a0, a2 = a0, a3 = a0;

  int j = beg + g;
  for (; j + 12 < end; j += 16) {
    const int se0 = srcet[j];
    const int se1 = srcet[j + 4];
    const int se2 = srcet[j + 8];
    const int se3 = srcet[j + 12];
    const uint2 r0 = *(const uint2*)(hb + ((size_t)(se0 >> 2) << 6) + (t << 2));
    const uint2 r1 = *(const uint2*)(hb + ((size_t)(se1 >> 2) << 6) + (t << 2));
    const uint2 r2 = *(const uint2*)(hb + ((size_t)(se2 >> 2) << 6) + (t << 2));
    const uint2 r3 = *(const uint2*)(hb + ((size_t)(se3 >> 2) << 6) + (t << 2));
    const float4 v0 = unpack4(r0);
    const float4 v1 = unpack4(r1);
    const float4 v2 = unpack4(r2);
    const float4 v3 = unpack4(r3);
    ACCUM(se0, v0);
    ACCUM(se1, v1);
    ACCUM(se2, v2);
    ACCUM(se3, v3);
  }
  for (; j < end; j += 4) {
    const int se0 = srcet[j];
    const uint2 r0 = *(const uint2*)(hb + ((size_t)(se0 >> 2) << 6) + (t << 2));
    const float4 v0 = unpack4(r0);
    ACCUM(se0, v0);
  }

#pragma unroll
  for (int off = 16; off <= 32; off <<= 1) {
    a0.x += __shfl_xor(a0.x, off); a0.y += __shfl_xor(a0.y, off);
    a0.z += __shfl_xor(a0.z, off); a0.w += __shfl_xor(a0.w, off);
    a1.x += __shfl_xor(a1.x, off); a1.y += __shfl_xor(a1.y, off);
    a1.z += __shfl_xor(a1.z, off); a1.w += __shfl_xor(a1.w, off);
    a2.x += __shfl_xor(a2.x, off); a2.y += __shfl_xor(a2.y, off);
    a2.z += __shfl_xor(a2.z, off); a2.w += __shfl_xor(a2.w, off);
    a3.x += __shfl_xor(a3.x, off); a3.y += __shfl_xor(a3.y, off);
    a3.z += __shfl_xor(a3.z, off); a3.w += __shfl_xor(a3.w, off);
  }

  const float4 res = (g == 0) ? a0 : (g == 1) ? a1 : (g == 2) ? a2 : a3;
  uint2 p;
  p.x = f2bf(res.x) | (f2bf(res.y) << 16);
  p.y = f2bf(res.z) | (f2bf(res.w) << 16);
  *(uint2*)(aggr_bf + ((size_t)n << 8) + (g << 6) + (t << 2)) = p;
}

// == dense (LDS-tiled, bf16 in/out): hb_out = bf16(relu(sum_r aggr@Wrel + h@Wloop + b)) ==
__global__ __launch_bounds__(256) void rgcn_dense_t(
    const ushort* __restrict__ aggr_bf, const ushort* __restrict__ hb_in,
    const float* __restrict__ Wrel, const float* __restrict__ Wloop,
    const float* __restrict__ brel, ushort* __restrict__ hb_out, int N) {
  __shared__ float tile[64 * 65];
  const int tid = threadIdx.x;
  const int lane = tid & 63;
  const int wv = tid >> 6;
  const int c0 = __builtin_amdgcn_readfirstlane(wv << 4);
  const int n0 = blockIdx.x * 64;

  float acc[16];
#pragma unroll
  for (int jj = 0; jj < 16; ++jj) acc[jj] = brel[c0 + jj];

#pragma unroll 1
  for (int m = 0; m < 5; ++m) {
    __syncthreads();
#pragma unroll
    for (int q = 0; q < 2; ++q) {
      const int f = q * 256 + tid;  // 0..511
      const int row = f >> 3;       // 0..63
      const int c8 = (f & 7) << 3;  // 0..56
      const int nn = n0 + row;
      float v[8] = {0.f, 0.f, 0.f, 0.f, 0.f, 0.f, 0.f, 0.f};
      if (nn < N) {
        const ushort* s = (m < 4) ? (aggr_bf + ((size_t)nn << 8) + (m << 6) + c8)
                                  : (hb_in + ((size_t)nn << 6) + c8);
        const uint4 raw = *(const uint4*)s;
        unpack8(raw, v);
      }
      float* d = tile + row * 65 + c8;
#pragma unroll
      for (int k = 0; k < 8; ++k) d[k] = v[k];
    }
    __syncthreads();
    const float* __restrict__ W =
        (m < 4) ? (Wrel + (size_t)m * DD * DD) : Wloop;
    const float* trow = tile + lane * 65;
#pragma unroll
    for (int k = 0; k < DD; ++k) {
      const float hk = trow[k];
#pragma unroll
      for (int jj = 0; jj < 16; ++jj)
        acc[jj] = fmaf(hk, W[k * DD + c0 + jj], acc[jj]);
    }
  }

  __syncthreads();
  {
    float* d = tile + lane * 65 + c0;
#pragma unroll
    for (int jj = 0; jj < 16; ++jj) d[jj] = fmaxf(acc[jj], 0.f);
  }
  __syncthreads();
#pragma unroll
  for (int q = 0; q < 2; ++q) {
    const int f = q * 256 + tid;
    const int row = f >> 3;
    const int c8 = (f & 7) << 3;
    const int nn = n0 + row;
    if (nn < N) {
      const float* s = tile + row * 65 + c8;
      uint4 p;
      p.x = f2bf(s[0]) | (f2bf(s[1]) << 16);
      p.y = f2bf(s[2]) | (f2bf(s[3]) << 16);
      p.z = f2bf(s[4]) | (f2bf(s[5]) << 16);
      p.w = f2bf(s[6]) | (f2bf(s[7]) << 16);
      *(uint4*)(hb_out + ((size_t)nn << 6) + c8) = p;
    }
  }
}

// ===== GAT projection (LDS-tiled, bf16 in): el/er/y per node + global max(el) =====
// y[n] = (h[n]@Wg) . Wd  — z is never materialized (head is linear in hg).
__global__ __launch_bounds__(256) void gemm_gat_t(
    const ushort* __restrict__ hb_in, const float* __restrict__ Wg,
    const float* __restrict__ al, const float* __restrict__ ar,
    const float* __restrict__ Wd, float* __restrict__ el,
    float* __restrict__ er, float* __restrict__ y,
    unsigned* __restrict__ genc, int N) {
  __shared__ float tile[64 * 65];
  __shared__ float sel[4][64];
  __shared__ float ser[4][64];
  __shared__ float sy[4][64];
  const int tid = threadIdx.x;
  const int lane = tid & 63;
  const int wv = tid >> 6;
  const int c0 = __builtin_amdgcn_readfirstlane(wv << 4);
  const int n0 = blockIdx.x * 64;
  const int n = n0 + lane;

#pragma unroll
  for (int q = 0; q < 2; ++q) {
    const int f = q * 256 + tid;
    const int row = f >> 3;
    const int c8 = (f & 7) << 3;
    const int nn = n0 + row;
    float v[8] = {0.f, 0.f, 0.f, 0.f, 0.f, 0.f, 0.f, 0.f};
    if (nn < N) {
      const uint4 raw = *(const uint4*)(hb_in + ((size_t)nn << 6) + c8);
      unpack8(raw, v);
    }
    float* d = tile + row * 65 + c8;
#pragma unroll
    for (int k = 0; k < 8; ++k) d[k] = v[k];
  }
  __syncthreads();

  float acc[16];
#pragma unroll
  for (int jj = 0; jj < 16; ++jj) acc[jj] = 0.f;
  {
    const float* trow = tile + lane * 65;
#pragma unroll
    for (int k = 0; k < DD; ++k) {
      const float hk = trow[k];
#pragma unroll
      for (int jj = 0; jj < 16; ++jj)
        acc[jj] = fmaf(hk, Wg[k * DD + c0 + jj], acc[jj]);
    }
  }

  float pl = 0.f, pr = 0.f, py = 0.f;
#pragma unroll
  for (int jj = 0; jj < 16; ++jj) {
    pl = fmaf(acc[jj], al[c0 + jj], pl);
    pr = fmaf(acc[jj], ar[c0 + jj], pr);
    py = fmaf(acc[jj], Wd[c0 + jj], py);
  }
  sel[wv][lane] = pl;
  ser[wv][lane] = pr;
  sy[wv][lane] = py;
  __syncthreads();
  if (wv == 0) {
    float eln = sel[0][lane] + sel[1][lane] + sel[2][lane] + sel[3][lane];
    float ern = ser[0][lane] + ser[1][lane] + ser[2][lane] + ser[3][lane];
    float yn = sy[0][lane] + sy[1][lane] + sy[2][lane] + sy[3][lane];
    if (n < N) {
      el[n] = eln;
      er[n] = ern;
      y[n] = yn;
    }
    float mx = (n < N) ? eln : -1e30f;
#pragma unroll
    for (int off = 32; off > 0; off >>= 1) mx = fmaxf(mx, __shfl_xor(mx, off));
    if (lane == 0) atomicMax(genc, enc_f32(mx));
  }
}

// ===== scalar GAT aggregation + pooling, 16 lanes/node (latency-hiding geometry) =====
// out[g] += sum_n (sum_s w*y[s]) / (sum_s w);  el/y tables are 200 KB (L2-resident).
#define GSC_NPG 2                        // nodes per 16-lane group
#define GSC_NPB (16 * GSC_NPG)           // 32 nodes per block
__global__ __launch_bounds__(256) void gat_scalar(
    const float* __restrict__ el, const float* __restrict__ er,
    const float* __restrict__ y, const int* __restrict__ rowptr,
    const int* __restrict__ srcet, const unsigned* __restrict__ genc,
    const int* __restrict__ gids, float* __restrict__ out, int N, int B) {
  __shared__ float acc[256];
  for (int i = threadIdx.x; i < B; i += 256) acc[i] = 0.f;
  __syncthreads();
  const int grp = threadIdx.x >> 4;  // 0..15
  const int ln = threadIdx.x & 15;   // 0..15
  const float gmax = dec_f32(*genc);
  const int base = blockIdx.x * GSC_NPB + grp * GSC_NPG;

#pragma unroll
  for (int i = 0; i < GSC_NPG; ++i) {
    const int n = base + i;
    if (n < N) {
      const int beg = rowptr[n], end = rowptr[n + 1];
      const float ern = er[n];
      float mb = gmax + ern;  // upper bound on leaky(el[s]+ern): leaky monotone
      mb = (mb > 0.f) ? mb : 0.2f * mb;
      float num = 0.f, den = 0.f;
      for (int j = beg + ln; j < end; j += 16) {
        const int s = srcet[j] >> 2;
        float x = el[s] + ern;
        x = (x > 0.f) ? x : 0.2f * x;
        const float w = __expf(x - mb);
        num = fmaf(w, y[s], num);
        den += w;
      }
#pragma unroll
      for (int off = 1; off < 16; off <<= 1) {
        num += __shfl_xor(num, off);
        den += __shfl_xor(den, off);
      }
      if (ln == 0) atomicAdd(&acc[gids[n]], num / fmaxf(den, 1e-9f));
    }
  }
  __syncthreads();
  for (int i = threadIdx.x; i < B; i += 256) {
    const float v = acc[i];
    if (v != 0.f) unsafeAtomicAdd(out + i, v);
  }
}

__global__ void init_out_k(float* out, const float* bd, int n, unsigned* genc,
                           int* gcur, int CAP) {
  int i = blockIdx.x * blockDim.x + threadIdx.x;
  if (i < n) out[i] = bd[0];
  if (i < 256) gcur[i] = i * CAP;
  if (i == 0) *genc = enc_f32(-1e30f);
}

// ================= launch =================
extern "C" void kernel_launch(void* const* d_in, const int* in_sizes, int n_in,
                              void* d_out, int out_size, void* d_ws,
                              size_t ws_size, hipStream_t stream) {
  const float* h0 = (const float*)d_in[0];
  const float* Wrel = (const float*)d_in[1];
  const float* Wloop = (const float*)d_in[2];
  const float* brel = (const float*)d_in[3];
  const float* Wg = (const float*)d_in[4];
  const float* al = (const float*)d_in[5];
  const float* ar = (const float*)d_in[6];
  const float* Wd = (const float*)d_in[7];
  const float* bd = (const float*)d_in[8];
  const int* src = (const int*)d_in[9];
  const int* dst = (const int*)d_in[10];
  const int* et = (const int*)d_in[11];
  const int* gids = (const int*)d_in[12];

  const int N = in_sizes[0] / DD;
  const int E = in_sizes[9];
  const int L = in_sizes[2] / (DD * DD);
  float* out = (float*)d_out;
  const int CAP = (E / 256) * 2;  // fixed bucket capacity (2x mean)

  // ---- workspace layout ----
  char* wsb = (char*)d_ws;
  ushort* hbA = (ushort*)wsb;                    // N*64 bf16
  ushort* hbB = hbA + (size_t)N * DD;            // N*64 bf16
  ushort* aggr_bf = hbB + (size_t)N * DD;        // N*256 bf16 (25.6MB region)
  int* rowptr = (int*)(aggr_bf + (size_t)N * 256);  // N+1
  int* srcet = rowptr + N + 1;                   // E
  float* el = (float*)(srcet + E);               // N
  float* er = el + N;                            // N
  float* yv = er + N;                            // N
  int* gcur = (int*)(yv + N);                    // 256
  int* cbase = gcur + 256;                       // 256
  unsigned* genc = (unsigned*)(cbase + 256);     // 1
  unsigned* staging = (unsigned*)aggr_bf;        // 256*CAP uints (12.8MB)

  dim3 b256(256);
  const int grid_dense = (N + 63) / 64;
  const int grid_n4 = (N + 3) / 4;
  const int nfb = (E + EPB - 1) / EPB;
  const int ncb = (N + 255) >> 8;

  hipLaunchKernelGGL(init_out_k, dim3((max(out_size, 256) + 255) / 256), b256,
                     0, stream, out, bd, out_size, genc, gcur, CAP);

  // ---- CSR build (fixed-capacity buckets, (dst,rel)-sorted output) ----
  hipLaunchKernelGGL(f2_coarse, dim3(nfb), b256, 0, stream, src, dst, et, gcur,
                     staging, E);
  hipLaunchKernelGGL(cscan2, dim3(1), b256, 0, stream, gcur, cbase, rowptr, N,
                     E, CAP);
  hipLaunchKernelGGL(f3_fine4, dim3(ncb * 4), b256, 0, stream, staging, gcur,
                     cbase, rowptr, srcet, N, CAP);

  // ---- h0 -> bf16 ----
  hipLaunchKernelGGL(conv_bf16, dim3((N * DD / 4 + 255) / 256), b256, 0, stream,
                     h0, hbA, N * DD / 4);

  // ---- RGCN layers (bf16 features, f32 accumulate; dense stores post-relu) ----
  ushort* cur = hbA;
  ushort* nxt = hbB;
  for (int l = 0; l < L; ++l) {
    hipLaunchKernelGGL(gather_rel, dim3(grid_n4), b256, 0, stream, cur, rowptr,
                       srcet, aggr_bf, N);
    hipLaunchKernelGGL(rgcn_dense_t, dim3(grid_dense), b256, 0, stream, aggr_bf,
                       cur, Wrel + (size_t)l * 4 * DD * DD,
                       Wloop + (size_t)l * DD * DD, brel + (size_t)l * DD, nxt,
                       N);
    ushort* tmp = cur; cur = nxt; nxt = tmp;
  }

  // ---- GAT: project to el/er/y scalars, then scalar aggregation + pooling ----
  hipLaunchKernelGGL(gemm_gat_t, dim3(grid_dense), b256, 0, stream, cur, Wg, al,
                     ar, Wd, el, er, yv, genc, N);
  const int grid_gs = (N + GSC_NPB - 1) / GSC_NPB;
  hipLaunchKernelGGL(gat_scalar, dim3(grid_gs), b256, 0, stream, el, er, yv,
                     rowptr, srcet, genc, gids, out, N, out_size);
}

// Round 18
// 476.239 us; speedup vs baseline: 1.1937x; 1.0341x over previous
//
#include <hip/hip_runtime.h>

#define DD 64
#define EPB 1024  // edges per block in fill pipeline
#define NREP 8    // gcur replicas (anti-serialization)

__device__ __forceinline__ unsigned enc_f32(float x) {
  unsigned u = __float_as_uint(x);
  return (u & 0x80000000u) ? ~u : (u | 0x80000000u);
}
__device__ __forceinline__ float dec_f32(unsigned k) {
  return (k & 0x80000000u) ? __uint_as_float(k ^ 0x80000000u)
                           : __uint_as_float(~k);
}
__device__ __forceinline__ unsigned f2bf(float x) {
  unsigned u = __float_as_uint(x);
  return (u + 0x7fffu + ((u >> 16) & 1u)) >> 16;
}
__device__ __forceinline__ void unpack8(const uint4 raw, float* v) {
  v[0] = __uint_as_float(raw.x << 16);
  v[1] = __uint_as_float(raw.x & 0xffff0000u);
  v[2] = __uint_as_float(raw.y << 16);
  v[3] = __uint_as_float(raw.y & 0xffff0000u);
  v[4] = __uint_as_float(raw.z << 16);
  v[5] = __uint_as_float(raw.z & 0xffff0000u);
  v[6] = __uint_as_float(raw.w << 16);
  v[7] = __uint_as_float(raw.w & 0xffff0000u);
}
__device__ __forceinline__ float4 unpack4(const uint2 r) {
  return make_float4(__uint_as_float(r.x << 16),
                     __uint_as_float(r.x & 0xffff0000u),
                     __uint_as_float(r.y << 16),
                     __uint_as_float(r.y & 0xffff0000u));
}

// ================= f32 -> bf16 conversion (h0) =================
__global__ __launch_bounds__(256) void conv_bf16(const float* __restrict__ x,
                                                 ushort* __restrict__ xb,
                                                 int n4) {
  int i = blockIdx.x * 256 + threadIdx.x;
  if (i < n4) {
    float4 v = ((const float4*)x)[i];
    uint2 o;
    o.x = f2bf(v.x) | (f2bf(v.y) << 16);
    o.y = f2bf(v.z) | (f2bf(v.w) << 16);
    ((uint2*)xb)[i] = o;
  }
}

// ---- coarse scatter: LDS-reordered, replicated fixed-capacity bucket slices ----
// record = (d & 255) << 24 | se   (se = (src<<2)|et < 2^18)
// bucket cb's records live in NREP sub-runs: [cb*CAP + r*CAP8, gcur[r][cb])
__global__ __launch_bounds__(256) void f2_coarse(
    const int* __restrict__ src, const int* __restrict__ dst,
    const int* __restrict__ et, int* __restrict__ gcur,
    unsigned* __restrict__ staging, int E) {
  __shared__ int lcnt[256];
  __shared__ int sc[256];
  __shared__ int lbase[256];
  __shared__ int gb[256];
  __shared__ unsigned rec[EPB];
  __shared__ unsigned char rbk[EPB];

  const int t = threadIdx.x;
  const int base = blockIdx.x * EPB;
  const int rep = blockIdx.x & (NREP - 1);
  const int bc = min(EPB, E - base);

  lcnt[t] = 0;
  __syncthreads();

  int d_[EPB / 256], se_[EPB / 256], rk_[EPB / 256];
#pragma unroll
  for (int k = 0; k < EPB / 256; ++k) {
    const int e = base + k * 256 + t;
    if (e < E) {
      const int d = dst[e];
      d_[k] = d;
      se_[k] = (src[e] << 2) | et[e];
      rk_[k] = atomicAdd(&lcnt[d >> 8], 1);
    } else {
      d_[k] = -1;
    }
  }
  __syncthreads();

  const int lv = lcnt[t];
  sc[t] = lv;
  __syncthreads();
#pragma unroll
  for (int off = 1; off < 256; off <<= 1) {
    const int add = (t >= off) ? sc[t - off] : 0;
    __syncthreads();
    sc[t] += add;
    __syncthreads();
  }
  lbase[t] = sc[t] - lv;
  gb[t] = lv ? atomicAdd(&gcur[rep * 256 + t], lv) : 0;
  __syncthreads();

#pragma unroll
  for (int k = 0; k < EPB / 256; ++k) {
    if (d_[k] >= 0) {
      const int cb = d_[k] >> 8;
      const int pos = lbase[cb] + rk_[k];
      rec[pos] = ((unsigned)(d_[k] & 255) << 24) | (unsigned)se_[k];
      rbk[pos] = (unsigned char)cb;
    }
  }
  __syncthreads();

  for (int idx = t; idx < bc; idx += 256) {
    const int cb = rbk[idx];
    staging[gb[cb] + (idx - lbase[cb])] = rec[idx];
  }
}

// ---- scan bucket counts (sum of NREP sub-counts) -> cbase; set rowptr[N] ----
__global__ __launch_bounds__(256) void cscan2(const int* __restrict__ gcur,
                                              int* __restrict__ cbase,
                                              int* __restrict__ rowptr, int N,
                                              int E, int CAP, int CAP8) {
  __shared__ int s[256];
  const int t = threadIdx.x;
  int c = 0;
#pragma unroll
  for (int r = 0; r < NREP; ++r)
    c += gcur[r * 256 + t] - (t * CAP + r * CAP8);
  s[t] = c;
  __syncthreads();
#pragma unroll
  for (int off = 1; off < 256; off <<= 1) {
    const int add = (t >= off) ? s[t - off] : 0;
    __syncthreads();
    s[t] += add;
    __syncthreads();
  }
  cbase[t] = s[t] - c;
  if (t == 0) rowptr[N] = E;
}

// ---- fine placement, 4 sub-blocks per bucket, (dst,rel)-sorted output ----
__global__ __launch_bounds__(256) void f3_fine4(
    const unsigned* __restrict__ staging, const int* __restrict__ gcur,
    const int* __restrict__ cbase, int* __restrict__ rowptr,
    int* __restrict__ srcet, int N, int CAP, int CAP8) {
  __shared__ int hist[256];
  __shared__ int sc[256];
  __shared__ int lcur[256];
  __shared__ int before;
  const int cb = blockIdx.x >> 2;
  const int sub = blockIdx.x & 3;
  const int t = threadIdx.x;
  const int dlo = sub << 6;

  hist[t] = 0;
  if (t == 0) before = 0;
  __syncthreads();

  int myb = 0;
#pragma unroll 1
  for (int r = 0; r < NREP; ++r) {
    const int s0 = cb * CAP + r * CAP8;
    const int s1 = gcur[r * 256 + cb];
    for (int i = s0 + t; i < s1; i += 256) {
      const unsigned rc = staging[i];
      const int dl = (int)(rc >> 24);
      const int off = dl - dlo;
      if ((unsigned)off < 64u)
        atomicAdd(&hist[(off << 2) | (int)(rc & 3u)], 1);
      else if (dl < dlo)
        ++myb;
    }
  }
#pragma unroll
  for (int off = 32; off > 0; off >>= 1) myb += __shfl_down(myb, off);
  if ((t & 63) == 0 && myb) atomicAdd(&before, myb);
  __syncthreads();

  const int v = hist[t];
  sc[t] = v;
  __syncthreads();
#pragma unroll
  for (int off = 1; off < 256; off <<= 1) {
    const int add = (t >= off) ? sc[t - off] : 0;
    __syncthreads();
    sc[t] += add;
    __syncthreads();
  }
  const int base = cbase[cb] + before + sc[t] - v;
  lcur[t] = base;
  if ((t & 3) == 0) {
    const int dn = (cb << 8) + dlo + (t >> 2);
    if (dn < N) rowptr[dn] = base;
  }
  __syncthreads();

#pragma unroll 1
  for (int r = 0; r < NREP; ++r) {
    const int s0 = cb * CAP + r * CAP8;
    const int s1 = gcur[r * 256 + cb];
    for (int i = s0 + t; i < s1; i += 256) {
      const unsigned rc = staging[i];
      const int dl = (int)(rc >> 24);
      const int off = dl - dlo;
      if ((unsigned)off < 64u) {
        const int pos = atomicAdd(&lcur[(off << 2) | (int)(rc & 3u)], 1);
        srcet[pos] = (int)(rc & 0xFFFFFFu);
      }
    }
  }
}

// ====== per-node relation gather (bf16 rows, 16 lanes/edge, 4 in flight) ======
#define ACCUM(se, v)                                                         \
  {                                                                          \
    const int r_ = (se) & 3;                                                 \
    if (r_ == 0) { a0.x += v.x; a0.y += v.y; a0.z += v.z; a0.w += v.w; }     \
    else if (r_ == 1) { a1.x += v.x; a1.y += v.y; a1.z += v.z; a1.w += v.w; }\
    else if (r_ == 2) { a2.x += v.x; a2.y += v.y; a2.z += v.z; a2.w += v.w; }\
    else { a3.x += v.x; a3.y += v.y; a3.z += v.z; a3.w += v.w; }             \
  }

__global__ __launch_bounds__(256) void gather_rel(
    const ushort* __restrict__ hb, const int* __restrict__ rowptr,
    const int* __restrict__ srcet, ushort* __restrict__ aggr_bf, int N) {
  const int n = blockIdx.x * 4 + (threadIdx.x >> 6);
  const int lane = threadIdx.x & 63;
  const int g = lane >> 4;    // edge slot 0..3
  const int t = lane & 15;    // elements [4t, 4t+4)
  if (n >= N) return;
  const int beg = rowptr[n], end = rowptr[n + 1];

  float4 a0 = make_float4(0.f, 0.f, 0.f, 0.f);
  float4 a1 = a0, a2 = a0, a3 = a0;

  int j = beg + g;
  for (; j + 12 < end; j += 16) {
    const int se0 = srcet[j];
    const int se1 = srcet[j + 4];
    const int se2 = srcet[j + 8];
    const int se3 = srcet[j + 12];
    const uint2 r0 = *(const uint2*)(hb + ((size_t)(se0 >> 2) << 6) + (t << 2));
    const uint2 r1 = *(const uint2*)(hb + ((size_t)(se1 >> 2) << 6) + (t << 2));
    const uint2 r2 = *(const uint2*)(hb + ((size_t)(se2 >> 2) << 6) + (t << 2));
    const uint2 r3 = *(const uint2*)(hb + ((size_t)(se3 >> 2) << 6) + (t << 2));
    const float4 v0 = unpack4(r0);
    const float4 v1 = unpack4(r1);
    const float4 v2 = unpack4(r2);
    const float4 v3 = unpack4(r3);
    ACCUM(se0, v0);
    ACCUM(se1, v1);
    ACCUM(se2, v2);
    ACCUM(se3, v3);
  }
  for (; j < end; j += 4) {
    const int se0 = srcet[j];
    const uint2 r0 = *(const uint2*)(hb + ((size_t)(se0 >> 2) << 6) + (t << 2));
    const float4 v0 = unpack4(r0);
    ACCUM(se0, v0);
  }

#pragma unroll
  for (int off = 16; off <= 32; off <<= 1) {
    a0.x += __shfl_xor(a0.x, off); a0.y += __shfl_xor(a0.y, off);
    a0.z += __shfl_xor(a0.z, off); a0.w += __shfl_xor(a0.w, off);
    a1.x += __shfl_xor(a1.x, off); a1.y += __shfl_xor(a1.y, off);
    a1.z += __shfl_xor(a1.z, off); a1.w += __shfl_xor(a1.w, off);
    a2.x += __shfl_xor(a2.x, off); a2.y += __shfl_xor(a2.y, off);
    a2.z += __shfl_xor(a2.z, off); a2.w += __shfl_xor(a2.w, off);
    a3.x += __shfl_xor(a3.x, off); a3.y += __shfl_xor(a3.y, off);
    a3.z += __shfl_xor(a3.z, off); a3.w += __shfl_xor(a3.w, off);
  }

  const float4 res = (g == 0) ? a0 : (g == 1) ? a1 : (g == 2) ? a2 : a3;
  uint2 p;
  p.x = f2bf(res.x) | (f2bf(res.y) << 16);
  p.y = f2bf(res.z) | (f2bf(res.w) << 16);
  *(uint2*)(aggr_bf + ((size_t)n << 8) + (g << 6) + (t << 2)) = p;
}

// == dense (LDS-tiled, bf16 in/out): hb_out = bf16(relu(sum_r aggr@Wrel + h@Wloop + b)) ==
__global__ __launch_bounds__(256) void rgcn_dense_t(
    const ushort* __restrict__ aggr_bf, const ushort* __restrict__ hb_in,
    const float* __restrict__ Wrel, const float* __restrict__ Wloop,
    const float* __restrict__ brel, ushort* __restrict__ hb_out, int N) {
  __shared__ float tile[64 * 65];
  const int tid = threadIdx.x;
  const int lane = tid & 63;
  const int wv = tid >> 6;
  const int c0 = __builtin_amdgcn_readfirstlane(wv << 4);
  const int n0 = blockIdx.x * 64;

  float acc[16];
#pragma unroll
  for (int jj = 0; jj < 16; ++jj) acc[jj] = brel[c0 + jj];

#pragma unroll 1
  for (int m = 0; m < 5; ++m) {
    __syncthreads();
#pragma unroll
    for (int q = 0; q < 2; ++q) {
      const int f = q * 256 + tid;  // 0..511
      const int row = f >> 3;       // 0..63
      const int c8 = (f & 7) << 3;  // 0..56
      const int nn = n0 + row;
      float v[8] = {0.f, 0.f, 0.f, 0.f, 0.f, 0.f, 0.f, 0.f};
      if (nn < N) {
        const ushort* s = (m < 4) ? (aggr_bf + ((size_t)nn << 8) + (m << 6) + c8)
                                  : (hb_in + ((size_t)nn << 6) + c8);
        const uint4 raw = *(const uint4*)s;
        unpack8(raw, v);
      }
      float* d = tile + row * 65 + c8;
#pragma unroll
      for (int k = 0; k < 8; ++k) d[k] = v[k];
    }
    __syncthreads();
    const float* __restrict__ W =
        (m < 4) ? (Wrel + (size_t)m * DD * DD) : Wloop;
    const float* trow = tile + lane * 65;
#pragma unroll
    for (int k = 0; k < DD; ++k) {
      const float hk = trow[k];
#pragma unroll
      for (int jj = 0; jj < 16; ++jj)
        acc[jj] = fmaf(hk, W[k * DD + c0 + jj], acc[jj]);
    }
  }

  __syncthreads();
  {
    float* d = tile + lane * 65 + c0;
#pragma unroll
    for (int jj = 0; jj < 16; ++jj) d[jj] = fmaxf(acc[jj], 0.f);
  }
  __syncthreads();
#pragma unroll
  for (int q = 0; q < 2; ++q) {
    const int f = q * 256 + tid;
    const int row = f >> 3;
    const int c8 = (f & 7) << 3;
    const int nn = n0 + row;
    if (nn < N) {
      const float* s = tile + row * 65 + c8;
      uint4 p;
      p.x = f2bf(s[0]) | (f2bf(s[1]) << 16);
      p.y = f2bf(s[2]) | (f2bf(s[3]) << 16);
      p.z = f2bf(s[4]) | (f2bf(s[5]) << 16);
      p.w = f2bf(s[6]) | (f2bf(s[7]) << 16);
      *(uint4*)(hb_out + ((size_t)nn << 6) + c8) = p;
    }
  }
}

// ===== GAT projection (LDS-tiled, bf16 in): el/er/y per node + global max(el) =====
// y[n] = (h[n]@Wg) . Wd  — z is never materialized (head is linear in hg).
__global__ __launch_bounds__(256) void gemm_gat_t(
    const ushort* __restrict__ hb_in, const float* __restrict__ Wg,
    const float* __restrict__ al, const float* __restrict__ ar,
    const float* __restrict__ Wd, float* __restrict__ el,
    float* __restrict__ er, float* __restrict__ y,
    unsigned* __restrict__ genc, int N) {
  __shared__ float tile[64 * 65];
  __shared__ float sel[4][64];
  __shared__ float ser[4][64];
  __shared__ float sy[4][64];
  const int tid = threadIdx.x;
  const int lane = tid & 63;
  const int wv = tid >> 6;
  const int c0 = __builtin_amdgcn_readfirstlane(wv << 4);
  const int n0 = blockIdx.x * 64;
  const int n = n0 + lane;

#pragma unroll
  for (int q = 0; q < 2; ++q) {
    const int f = q * 256 + tid;
    const int row = f >> 3;
    const int c8 = (f & 7) << 3;
    const int nn = n0 + row;
    float v[8] = {0.f, 0.f, 0.f, 0.f, 0.f, 0.f, 0.f, 0.f};
    if (nn < N) {
      const uint4 raw = *(const uint4*)(hb_in + ((size_t)nn << 6) + c8);
      unpack8(raw, v);
    }
    float* d = tile + row * 65 + c8;
#pragma unroll
    for (int k = 0; k < 8; ++k) d[k] = v[k];
  }
  __syncthreads();

  float acc[16];
#pragma unroll
  for (int jj = 0; jj < 16; ++jj) acc[jj] = 0.f;
  {
    const float* trow = tile + lane * 65;
#pragma unroll
    for (int k = 0; k < DD; ++k) {
      const float hk = trow[k];
#pragma unroll
      for (int jj = 0; jj < 16; ++jj)
        acc[jj] = fmaf(hk, Wg[k * DD + c0 + jj], acc[jj]);
    }
  }

  float pl = 0.f, pr = 0.f, py = 0.f;
#pragma unroll
  for (int jj = 0; jj < 16; ++jj) {
    pl = fmaf(acc[jj], al[c0 + jj], pl);
    pr = fmaf(acc[jj], ar[c0 + jj], pr);
    py = fmaf(acc[jj], Wd[c0 + jj], py);
  }
  sel[wv][lane] = pl;
  ser[wv][lane] = pr;
  sy[wv][lane] = py;
  __syncthreads();
  if (wv == 0) {
    float eln = sel[0][lane] + sel[1][lane] + sel[2][lane] + sel[3][lane];
    float ern = ser[0][lane] + ser[1][lane] + ser[2][lane] + ser[3][lane];
    float yn = sy[0][lane] + sy[1][lane] + sy[2][lane] + sy[3][lane];
    if (n < N) {
      el[n] = eln;
      er[n] = ern;
      y[n] = yn;
    }
    float mx = (n < N) ? eln : -1e30f;
#pragma unroll
    for (int off = 32; off > 0; off >>= 1) mx = fmaxf(mx, __shfl_xor(mx, off));
    if (lane == 0) atomicMax(genc, enc_f32(mx));
  }
}

// ===== scalar GAT aggregation + pooling, 16 lanes/node =====
#define GSC_NPG 2
#define GSC_NPB (16 * GSC_NPG)
__global__ __launch_bounds__(256) void gat_scalar(
    const float* __restrict__ el, const float* __restrict__ er,
    const float* __restrict__ y, const int* __restrict__ rowptr,
    const int* __restrict__ srcet, const unsigned* __restrict__ genc,
    const int* __restrict__ gids, float* __restrict__ out, int N, int B) {
  __shared__ float acc[256];
  for (int i = threadIdx.x; i < B; i += 256) acc[i] = 0.f;
  __syncthreads();
  const int grp = threadIdx.x >> 4;
  const int ln = threadIdx.x & 15;
  const float gmax = dec_f32(*genc);
  const int base = blockIdx.x * GSC_NPB + grp * GSC_NPG;

#pragma unroll
  for (int i = 0; i < GSC_NPG; ++i) {
    const int n = base + i;
    if (n < N) {
      const int beg = rowptr[n], end = rowptr[n + 1];
      const float ern = er[n];
      float mb = gmax + ern;
      mb = (mb > 0.f) ? mb : 0.2f * mb;
      float num = 0.f, den = 0.f;
      for (int j = beg + ln; j < end; j += 16) {
        const int s = srcet[j] >> 2;
        float x = el[s] + ern;
        x = (x > 0.f) ? x : 0.2f * x;
        const float w = __expf(x - mb);
        num = fmaf(w, y[s], num);
        den += w;
      }
#pragma unroll
      for (int off = 1; off < 16; off <<= 1) {
        num += __shfl_xor(num, off);
        den += __shfl_xor(den, off);
      }
      if (ln == 0) atomicAdd(&acc[gids[n]], num / fmaxf(den, 1e-9f));
    }
  }
  __syncthreads();
  for (int i = threadIdx.x; i < B; i += 256) {
    const float v = acc[i];
    if (v != 0.f) unsafeAtomicAdd(out + i, v);
  }
}

__global__ void init_out_k(float* out, const float* bd, int n, unsigned* genc,
                           int* gcur, int CAP, int CAP8) {
  int i = blockIdx.x * blockDim.x + threadIdx.x;
  if (i < n) out[i] = bd[0];
  if (i < 256 * NREP) {
    const int r = i >> 8;
    const int b = i & 255;
    gcur[i] = b * CAP + r * CAP8;
  }
  if (i == 0) *genc = enc_f32(-1e30f);
}

// ================= launch =================
extern "C" void kernel_launch(void* const* d_in, const int* in_sizes, int n_in,
                              void* d_out, int out_size, void* d_ws,
                              size_t ws_size, hipStream_t stream) {
  const float* h0 = (const float*)d_in[0];
  const float* Wrel = (const float*)d_in[1];
  const float* Wloop = (const float*)d_in[2];
  const float* brel = (const float*)d_in[3];
  const float* Wg = (const float*)d_in[4];
  const float* al = (const float*)d_in[5];
  const float* ar = (const float*)d_in[6];
  const float* Wd = (const float*)d_in[7];
  const float* bd = (const float*)d_in[8];
  const int* src = (const int*)d_in[9];
  const int* dst = (const int*)d_in[10];
  const int* et = (const int*)d_in[11];
  const int* gids = (const int*)d_in[12];

  const int N = in_sizes[0] / DD;
  const int E = in_sizes[9];
  const int L = in_sizes[2] / (DD * DD);
  float* out = (float*)d_out;
  // per-replica sub-slice capacity: 2x its expected load, 64-aligned
  const int CAP8 = ((E / (256 * NREP)) * 2 + 63) & ~63;
  const int CAP = CAP8 * NREP;

  // ---- workspace layout ----
  char* wsb = (char*)d_ws;
  ushort* hbA = (ushort*)wsb;                    // N*64 bf16
  ushort* hbB = hbA + (size_t)N * DD;            // N*64 bf16
  ushort* aggr_bf = hbB + (size_t)N * DD;        // N*256 bf16 (25.6MB region)
  int* rowptr = (int*)(aggr_bf + (size_t)N * 256);  // N+1
  int* srcet = rowptr + N + 1;                   // E
  float* el = (float*)(srcet + E);               // N
  float* er = el + N;                            // N
  float* yv = er + N;                            // N
  int* gcur = (int*)(yv + N);                    // 256*NREP
  int* cbase = gcur + 256 * NREP;                // 256
  unsigned* genc = (unsigned*)(cbase + 256);     // 1
  unsigned* staging = (unsigned*)aggr_bf;        // 256*CAP uints (~13.1MB)

  dim3 b256(256);
  const int grid_dense = (N + 63) / 64;
  const int grid_n4 = (N + 3) / 4;
  const int nfb = (E + EPB - 1) / EPB;
  const int ncb = (N + 255) >> 8;

  hipLaunchKernelGGL(init_out_k, dim3((max(out_size, 256 * NREP) + 255) / 256),
                     b256, 0, stream, out, bd, out_size, genc, gcur, CAP, CAP8);

  // ---- CSR build (replicated fixed-capacity buckets, (dst,rel)-sorted) ----
  hipLaunchKernelGGL(f2_coarse, dim3(nfb), b256, 0, stream, src, dst, et, gcur,
                     staging, E);
  hipLaunchKernelGGL(cscan2, dim3(1), b256, 0, stream, gcur, cbase, rowptr, N,
                     E, CAP, CAP8);
  hipLaunchKernelGGL(f3_fine4, dim3(ncb * 4), b256, 0, stream, staging, gcur,
                     cbase, rowptr, srcet, N, CAP, CAP8);

  // ---- h0 -> bf16 ----
  hipLaunchKernelGGL(conv_bf16, dim3((N * DD / 4 + 255) / 256), b256, 0, stream,
                     h0, hbA, N * DD / 4);

  // ---- RGCN layers (bf16 features, f32 accumulate; dense stores post-relu) ----
  ushort* cur = hbA;
  ushort* nxt = hbB;
  for (int l = 0; l < L; ++l) {
    hipLaunchKernelGGL(gather_rel, dim3(grid_n4), b256, 0, stream, cur, rowptr,
                       srcet, aggr_bf, N);
    hipLaunchKernelGGL(rgcn_dense_t, dim3(grid_dense), b256, 0, stream, aggr_bf,
                       cur, Wrel + (size_t)l * 4 * DD * DD,
                       Wloop + (size_t)l * DD * DD, brel + (size_t)l * DD, nxt,
                       N);
    ushort* tmp = cur; cur = nxt; nxt = tmp;
  }

  // ---- GAT: project to el/er/y scalars, then scalar aggregation + pooling ----
  hipLaunchKernelGGL(gemm_gat_t, dim3(grid_dense), b256, 0, stream, cur, Wg, al,
                     ar, Wd, el, er, yv, genc, N);
  const int grid_gs = (N + GSC_NPB - 1) / GSC_NPB;
  hipLaunchKernelGGL(gat_scalar, dim3(grid_gs), b256, 0, stream, el, er, yv,
                     rowptr, srcet, genc, gids, out, N, out_size);
}